// Round 1
// baseline (371.052 us; speedup 1.0000x reference)
//
#include <hip/hip_runtime.h>
#include <hip/hip_bf16.h>
#include <cmath>

// Problem constants (from the reference)
#define B     128
#define CIN   8
#define COUT  64
#define K     33
#define L     4096
#define PAD   16
#define HID   128
#define NW    3

#define TILE_L 1024
#define RPT    4      // outputs per thread (contiguous)
#define COG    8      // cout per block

__device__ __forceinline__ float softplusf(float v) {
    return (v > 20.f) ? v : log1pf(expf(v));
}

// ---------------------------------------------------------------------------
// Kernel A: per-(b,ci) mean and unbiased std over L
// ---------------------------------------------------------------------------
__global__ __launch_bounds__(256) void states_kernel(
    const float* __restrict__ x, float* __restrict__ states)
{
    const int row = blockIdx.x;               // b*CIN + ci
    const float* xp = x + (size_t)row * L;
    float s = 0.f, ss = 0.f;
    for (int j = threadIdx.x; j < L / 4; j += 256) {
        float4 v = ((const float4*)xp)[j];
        s  += v.x + v.y + v.z + v.w;
        ss += v.x * v.x + v.y * v.y + v.z * v.z + v.w * v.w;
    }
    // wave64 reduce
    for (int off = 32; off; off >>= 1) {
        s  += __shfl_down(s,  off);
        ss += __shfl_down(ss, off);
    }
    __shared__ float rs[4], rss[4];
    const int wid = threadIdx.x >> 6;
    if ((threadIdx.x & 63) == 0) { rs[wid] = s; rss[wid] = ss; }
    __syncthreads();
    if (threadIdx.x == 0) {
        float S  = rs[0] + rs[1] + rs[2] + rs[3];
        float SS = rss[0] + rss[1] + rss[2] + rss[3];
        float mean = S / (float)L;
        float var  = fmaxf(SS - S * mean, 0.f) / (float)(L - 1);
        int b = row / CIN, ci = row % CIN;
        states[b * (2 * CIN) + ci]       = mean;
        states[b * (2 * CIN) + CIN + ci] = sqrtf(var);
    }
}

// ---------------------------------------------------------------------------
// Kernel B: agent MLP -> greedy action. argmax(q) == argmax(a) since
// v and mean(a) are uniform shifts across the NW axis -> skip value head.
// ---------------------------------------------------------------------------
__global__ __launch_bounds__(128) void action_kernel(
    const float* __restrict__ states,
    const float* __restrict__ fw, const float* __restrict__ fb,
    const float* __restrict__ aw1, const float* __restrict__ ab1,
    const float* __restrict__ aw2, const float* __restrict__ ab2,
    int* __restrict__ actions)
{
    const int b = blockIdx.x, j = threadIdx.x;
    __shared__ float s[2 * CIN];
    __shared__ float h[HID];
    __shared__ float ha[HID];
    if (j < 2 * CIN) s[j] = states[b * (2 * CIN) + j];
    __syncthreads();

    float acc = fb[j];
    #pragma unroll
    for (int i = 0; i < 2 * CIN; ++i) acc = fmaf(s[i], fw[i * HID + j], acc);
    h[j] = fmaxf(acc, 0.f);
    __syncthreads();

    float acc2 = ab1[j];
    for (int i = 0; i < HID; ++i) acc2 = fmaf(h[i], aw1[i * HID + j], acc2);
    ha[j] = fmaxf(acc2, 0.f);
    __syncthreads();

    if (j == 0) {
        float best = -1e30f; int bi = 0;
        for (int w = 0; w < NW; ++w) {
            float a = ab2[w];
            for (int i = 0; i < HID; ++i) a = fmaf(ha[i], aw2[i * NW + w], a);
            if (a > best) { best = a; bi = w; }   // strict > = first-max wins
        }
        actions[b] = bi;
    }
}

// ---------------------------------------------------------------------------
// Kernel C: build the wavelet kernel bank [NW][COUT][CIN][K]
// ---------------------------------------------------------------------------
__global__ __launch_bounds__(256) void bank_kernel(
    const float* __restrict__ sp, float* __restrict__ bank)
{
    const int t = blockIdx.x * blockDim.x + threadIdx.x;
    if (t >= NW * COUT * CIN) return;
    const int nw  = t / (COUT * CIN);
    const int rem = t - nw * (COUT * CIN);
    const int co  = rem / CIN, ci = rem % CIN;

    const float p = sp[(co * CIN + ci) * NW + nw];
    const float scale = softplusf(p) + 1e-6f;

    float ker[K];
    float mean = 0.f;
    #pragma unroll
    for (int k = 0; k < K; ++k) {
        float g  = (float)(k - K / 2);
        float xi = g / scale;
        float v;
        if (nw == 0) {
            v = expf(-0.5f * xi * xi) * cosf(5.f * xi);
        } else if (nw == 1) {
            v = 0.8673250705840776f * (1.f - xi * xi) * expf(-0.5f * xi * xi);
        } else {
            float sgn = (g > 0.f) ? 1.f : ((g < 0.f) ? -1.f : 0.f);
            v = sgn * expf(-fabsf(xi));
        }
        ker[k] = v; mean += v;
    }
    mean *= (1.f / (float)K);
    float nrm = 0.f;
    #pragma unroll
    for (int k = 0; k < K; ++k) { ker[k] -= mean; nrm += ker[k] * ker[k]; }
    const float inv = 1.f / (sqrtf(nrm) + 1e-6f);

    float* dst = bank + (size_t)t * K;   // t = ((nw*COUT)+co)*CIN+ci  -> [nw][co][ci][k]
    #pragma unroll
    for (int k = 0; k < K; ++k) dst[k] = ker[k] * inv;
}

// ---------------------------------------------------------------------------
// Kernel D: batched conv1d with per-batch selected kernel + soft shrinkage
// ---------------------------------------------------------------------------
__global__ __launch_bounds__(256) void conv_kernel(
    const float* __restrict__ x, const float* __restrict__ bank,
    const int* __restrict__ actions, const float* __restrict__ threshold,
    float* __restrict__ out)
{
    const int b   = blockIdx.z;
    const int co0 = blockIdx.y * COG;
    const int l0  = blockIdx.x * TILE_L;
    const int tid = threadIdx.x;

    __shared__ float xs[CIN][TILE_L + 2 * PAD];   // 8 x 1056 = 33.8 KB

    const int act = __builtin_amdgcn_readfirstlane(actions[b]);

    for (int idx = tid; idx < CIN * (TILE_L + 2 * PAD); idx += 256) {
        int ci = idx / (TILE_L + 2 * PAD);
        int j  = idx - ci * (TILE_L + 2 * PAD);
        int g  = l0 - PAD + j;
        xs[ci][j] = (g >= 0 && g < L) ? x[((size_t)b * CIN + ci) * L + g] : 0.f;
    }
    __syncthreads();

    float acc[COG][RPT];
    #pragma unroll
    for (int c = 0; c < COG; ++c)
        #pragma unroll
        for (int r = 0; r < RPT; ++r) acc[c][r] = 0.f;

    const int lt = tid * RPT;   // 0..1020, multiple of 4 -> 16B-aligned window
    const float* wbase = bank + ((size_t)act * COUT + co0) * (CIN * K);

    for (int ci = 0; ci < CIN; ++ci) {
        // register sliding window: x needed for outputs [lt..lt+3] is xs[ci][lt..lt+35]
        float xv[RPT + K - 1];
        const float4* xq = (const float4*)&xs[ci][lt];
        #pragma unroll
        for (int q2 = 0; q2 < (RPT + K - 1) / 4; ++q2) {
            float4 v = xq[q2];
            xv[4 * q2 + 0] = v.x; xv[4 * q2 + 1] = v.y;
            xv[4 * q2 + 2] = v.z; xv[4 * q2 + 3] = v.w;
        }
        #pragma unroll
        for (int c = 0; c < COG; ++c) {
            const float* wp = wbase + (c * CIN + ci) * K;   // wave-uniform -> s_load
            float wreg[K];
            #pragma unroll
            for (int k = 0; k < K; ++k) wreg[k] = wp[k];
            #pragma unroll
            for (int k = 0; k < K; ++k)
                #pragma unroll
                for (int r = 0; r < RPT; ++r)
                    acc[c][r] = fmaf(xv[k + r], wreg[k], acc[c][r]);
        }
    }

    const int lo = l0 + lt;
    #pragma unroll
    for (int c = 0; c < COG; ++c) {
        const int co = co0 + c;
        const float tau = softplusf(threshold[co]) + 1e-6f;
        float4 o;
        float y0 = acc[c][0], y1 = acc[c][1], y2 = acc[c][2], y3 = acc[c][3];
        o.x = copysignf(fmaxf(fabsf(y0) - tau, 0.f), y0);
        o.y = copysignf(fmaxf(fabsf(y1) - tau, 0.f), y1);
        o.z = copysignf(fmaxf(fabsf(y2) - tau, 0.f), y2);
        o.w = copysignf(fmaxf(fabsf(y3) - tau, 0.f), y3);
        *((float4*)&out[((size_t)b * COUT + co) * L + lo]) = o;
    }
}

// ---------------------------------------------------------------------------
extern "C" void kernel_launch(void* const* d_in, const int* in_sizes, int n_in,
                              void* d_out, int out_size, void* d_ws, size_t ws_size,
                              hipStream_t stream)
{
    const float* x           = (const float*)d_in[0];
    const float* superparams = (const float*)d_in[1];
    const float* threshold   = (const float*)d_in[2];
    const float* fw          = (const float*)d_in[3];
    const float* fb          = (const float*)d_in[4];
    // d_in[5..8] = vw1, vb1, vw2, vb2 -- value head is argmax-invariant, unused
    const float* aw1         = (const float*)d_in[9];
    const float* ab1         = (const float*)d_in[10];
    const float* aw2         = (const float*)d_in[11];
    const float* ab2         = (const float*)d_in[12];
    float* out = (float*)d_out;

    float* states = (float*)d_ws;                         // 2048 f32
    int*   actions = (int*)((char*)d_ws + 8192);          // 128 i32
    float* bank    = (float*)((char*)d_ws + 16384);       // 50688 f32

    states_kernel<<<B * CIN, 256, 0, stream>>>(x, states);
    action_kernel<<<B, 128, 0, stream>>>(states, fw, fb, aw1, ab1, aw2, ab2, actions);
    bank_kernel<<<(NW * COUT * CIN + 255) / 256, 256, 0, stream>>>(superparams, bank);
    conv_kernel<<<dim3(L / TILE_L, COUT / COG, B), 256, 0, stream>>>(
        x, bank, actions, threshold, out);
}

// Round 3
// 231.696 us; speedup vs baseline: 1.6015x; 1.6015x over previous
//
#include <hip/hip_runtime.h>
#include <hip/hip_bf16.h>
#include <cmath>

#define B     128
#define CIN   8
#define COUT  64
#define K     33
#define KP    36      // padded taps (multiple of 4; 288 = 9 * 32)
#define KKD   (KP * CIN)   // 288 reduction length, kk = tap*8 + ci
#define NSL   (KKD / 32)   // 9 MFMA K-slices
#define L     4096
#define PAD   16
#define HID   128
#define NW    3

#define TL    512            // l-tile per block
#define NROW  (TL + KP)      // 548 xT rows (pos range [l0-16, l0+TL+19])

typedef __attribute__((ext_vector_type(8))) short short8;
typedef __attribute__((ext_vector_type(4))) float f32x4;

__device__ __forceinline__ float softplusf(float v) {
    return (v > 20.f) ? v : log1pf(expf(v));
}

// ---------------------------------------------------------------------------
// Kernel A: fused per-batch stats + agent MLP -> greedy action.
// argmax(q) == argmax(a): value head & a.mean() are uniform across NW -> skip.
// ---------------------------------------------------------------------------
__global__ __launch_bounds__(256) void agent_kernel(
    const float* __restrict__ x,
    const float* __restrict__ fw, const float* __restrict__ fb,
    const float* __restrict__ aw1, const float* __restrict__ ab1,
    const float* __restrict__ aw2, const float* __restrict__ ab2,
    int* __restrict__ actions)
{
    const int b = blockIdx.x;
    const int tid = threadIdx.x;
    __shared__ float st[2 * CIN];
    __shared__ float h[HID];
    __shared__ float ha[HID];

    // ---- stats: 32 threads per ci row ----
    const int ci  = tid >> 5;
    const int sub = tid & 31;
    const float* xp = x + ((size_t)b * CIN + ci) * L;
    float s = 0.f, ss = 0.f;
    for (int j = sub; j < L / 4; j += 32) {
        float4 v = ((const float4*)xp)[j];
        s  += v.x + v.y + v.z + v.w;
        ss += v.x * v.x + v.y * v.y + v.z * v.z + v.w * v.w;
    }
    for (int m = 16; m; m >>= 1) {
        s  += __shfl_xor(s,  m);
        ss += __shfl_xor(ss, m);
    }
    if (sub == 0) {
        float mean = s / (float)L;
        float var  = fmaxf(ss - s * mean, 0.f) / (float)(L - 1);
        st[ci]       = mean;
        st[CIN + ci] = sqrtf(var);
    }
    __syncthreads();

    // ---- MLP (first 128 threads) ----
    const int j = tid;
    if (j < HID) {
        float acc = fb[j];
        #pragma unroll
        for (int i = 0; i < 2 * CIN; ++i) acc = fmaf(st[i], fw[i * HID + j], acc);
        h[j] = fmaxf(acc, 0.f);
    }
    __syncthreads();
    if (j < HID) {
        float acc2 = ab1[j];
        for (int i = 0; i < HID; ++i) acc2 = fmaf(h[i], aw1[i * HID + j], acc2);
        ha[j] = fmaxf(acc2, 0.f);
    }
    __syncthreads();
    if (j == 0) {
        float best = -1e30f; int bi = 0;
        for (int w = 0; w < NW; ++w) {
            float a = ab2[w];
            for (int i = 0; i < HID; ++i) a = fmaf(ha[i], aw2[i * NW + w], a);
            if (a > best) { best = a; bi = w; }
        }
        actions[b] = bi;
    }
}

// ---------------------------------------------------------------------------
// Kernel B: wavelet bank -> bf16, layout [nw][co][tap*8 + ci], taps padded to 36
// ---------------------------------------------------------------------------
__global__ __launch_bounds__(256) void bank_kernel(
    const float* __restrict__ sp, __hip_bfloat16* __restrict__ bankbf)
{
    const int t = blockIdx.x * blockDim.x + threadIdx.x;
    if (t >= NW * COUT * CIN) return;
    const int nw = t >> 9;
    const int co = (t >> 3) & 63;
    const int ci = t & 7;

    const float p = sp[(co * CIN + ci) * NW + nw];
    const float scale = softplusf(p) + 1e-6f;

    float ker[K];
    float mean = 0.f;
    #pragma unroll
    for (int k = 0; k < K; ++k) {
        float g  = (float)(k - K / 2);
        float xi = g / scale;
        float v;
        if (nw == 0) {
            v = expf(-0.5f * xi * xi) * cosf(5.f * xi);
        } else if (nw == 1) {
            v = 0.8673250705840776f * (1.f - xi * xi) * expf(-0.5f * xi * xi);
        } else {
            float sgn = (g > 0.f) ? 1.f : ((g < 0.f) ? -1.f : 0.f);
            v = sgn * expf(-fabsf(xi));
        }
        ker[k] = v; mean += v;
    }
    mean *= (1.f / (float)K);
    float nrm = 0.f;
    #pragma unroll
    for (int k = 0; k < K; ++k) { ker[k] -= mean; nrm += ker[k] * ker[k]; }
    const float inv = 1.f / (sqrtf(nrm) + 1e-6f);

    __hip_bfloat16* dst = bankbf + ((size_t)(nw * COUT + co)) * KKD + ci;
    #pragma unroll
    for (int k = 0; k < K; ++k) dst[k * CIN] = __float2bfloat16(ker[k] * inv);
    #pragma unroll
    for (int k = K; k < KP; ++k) dst[k * CIN] = __float2bfloat16(0.f);
}

// ---------------------------------------------------------------------------
// Kernel C: implicit-GEMM conv via MFMA 16x16x32 bf16 + soft shrinkage
//   D[co, l] = sum_kk W[co, kk] * X[kk, l],  kk = tap*8 + ci
//   X[kk, l] = x[ci][l + tap - 16]  (read from LDS xT[pos][ci], 16B rows)
// Each wave: all 4 co-tiles (A in regs, 36 frags), 1/4 of the l range.
// ---------------------------------------------------------------------------
__global__ __launch_bounds__(256, 2) void conv_kernel(
    const float* __restrict__ x, const __hip_bfloat16* __restrict__ bankbf,
    const int* __restrict__ actions, const float* __restrict__ threshold,
    float* __restrict__ out)
{
    const int b  = blockIdx.y;
    const int l0 = blockIdx.x * TL;
    const int tid = threadIdx.x;
    const int lane = tid & 63;
    const int w    = tid >> 6;        // wave id 0..3
    const int g    = lane >> 4;       // lane group 0..3
    const int ln   = lane & 15;

    __shared__ short8 xT[NROW];       // [pos][ci] bf16, one 16B row per pos

    // ---- stage x tile (bf16, transposed) ----
    {
        __hip_bfloat16* xb = (__hip_bfloat16*)xT;
        for (int idx = tid; idx < CIN * NROW; idx += 256) {
            int ci = idx / NROW;
            int r  = idx - ci * NROW;
            int gp = l0 - PAD + r;
            float f = (gp >= 0 && gp < L) ? x[((size_t)b * CIN + ci) * L + gp] : 0.f;
            xb[r * CIN + ci] = __float2bfloat16(f);
        }
    }

    // ---- A fragments: weights for all 64 co, 9 slices ----
    const int act = __builtin_amdgcn_readfirstlane(actions[b]);
    const short8* wq = (const short8*)(bankbf + (size_t)act * COUT * KKD);
    // per co row: KKD/8 = 36 short8; frag index within row = 4*s + g
    short8 aQ[4][NSL];
    #pragma unroll
    for (int ct = 0; ct < 4; ++ct) {
        const short8* wrow = wq + (ct * 16 + ln) * (KKD / 8);
        #pragma unroll
        for (int s = 0; s < NSL; ++s) aQ[ct][s] = wrow[4 * s + g];
    }

    // ---- per-lane shrink thresholds: tau[ct][j] for co = ct*16 + 4*g + j ----
    float tau[4][4];
    #pragma unroll
    for (int ct = 0; ct < 4; ++ct)
        #pragma unroll
        for (int jj = 0; jj < 4; ++jj)
            tau[ct][jj] = softplusf(threshold[ct * 16 + 4 * g + jj]) + 1e-6f;

    __syncthreads();

    // ---- main loop: wave w covers local l in [w*128, w*128+128) ----
    const int wl0 = w * (TL / 4);
    for (int lt = 0; lt < (TL / 4) / 16; ++lt) {
        const int lbase = wl0 + lt * 16;
        const int row0  = lbase + ln + g;    // + 4*s per slice
        f32x4 acc[4] = {{0.f,0.f,0.f,0.f},{0.f,0.f,0.f,0.f},
                        {0.f,0.f,0.f,0.f},{0.f,0.f,0.f,0.f}};
        #pragma unroll
        for (int s = 0; s < NSL; ++s) {
            short8 bfrag = xT[row0 + 4 * s];
            acc[0] = __builtin_amdgcn_mfma_f32_16x16x32_bf16(aQ[0][s], bfrag, acc[0], 0, 0, 0);
            acc[1] = __builtin_amdgcn_mfma_f32_16x16x32_bf16(aQ[1][s], bfrag, acc[1], 0, 0, 0);
            acc[2] = __builtin_amdgcn_mfma_f32_16x16x32_bf16(aQ[2][s], bfrag, acc[2], 0, 0, 0);
            acc[3] = __builtin_amdgcn_mfma_f32_16x16x32_bf16(aQ[3][s], bfrag, acc[3], 0, 0, 0);
        }
        // epilogue: C/D layout col = ln (l), row = 4*g + j (co within tile)
        #pragma unroll
        for (int ct = 0; ct < 4; ++ct) {
            const int co = ct * 16 + 4 * g;
            #pragma unroll
            for (int jj = 0; jj < 4; ++jj) {
                float y = acc[ct][jj];
                float r = copysignf(fmaxf(fabsf(y) - tau[ct][jj], 0.f), y);
                out[((size_t)b * COUT + co + jj) * L + l0 + lbase + ln] = r;
            }
        }
    }
}

// ---------------------------------------------------------------------------
extern "C" void kernel_launch(void* const* d_in, const int* in_sizes, int n_in,
                              void* d_out, int out_size, void* d_ws, size_t ws_size,
                              hipStream_t stream)
{
    const float* x           = (const float*)d_in[0];
    const float* superparams = (const float*)d_in[1];
    const float* threshold   = (const float*)d_in[2];
    const float* fw          = (const float*)d_in[3];
    const float* fb          = (const float*)d_in[4];
    // d_in[5..8] = value head (argmax-invariant, unused)
    const float* aw1         = (const float*)d_in[9];
    const float* ab1         = (const float*)d_in[10];
    const float* aw2         = (const float*)d_in[11];
    const float* ab2         = (const float*)d_in[12];
    float* out = (float*)d_out;

    int* actions            = (int*)d_ws;                         // 128 i32
    __hip_bfloat16* bankbf  = (__hip_bfloat16*)((char*)d_ws + 1024); // 3*64*288 bf16

    agent_kernel<<<B, 256, 0, stream>>>(x, fw, fb, aw1, ab1, aw2, ab2, actions);
    bank_kernel<<<(NW * COUT * CIN + 255) / 256, 256, 0, stream>>>(superparams, bankbf);
    conv_kernel<<<dim3(L / TL, B), 256, 0, stream>>>(x, bankbf, actions, threshold, out);
}